// Round 1
// baseline (340.924 us; speedup 1.0000x reference)
//
#include <hip/hip_runtime.h>
#include <math.h>

#define NJ 17
#define NP 14
#define NCH 59   // 17 + 3*14
#define BATCH 256

__constant__ int c_par0[NP] = {0, 1, 2, 0, 4, 5, 0, 8, 14, 15, 8, 11, 12, 8};
__constant__ int c_par1[NP] = {1, 2, 3, 4, 5, 6, 8, 14, 15, 16, 11, 12, 13, 10};

// One block per (b, c) slice of middle_out[b, c, :, :] (64x64 = 4096 cells).
// Computes  partial[b*59 + c] = sum_cells (tgt(cell) - middle_out[b,c,cell])^2
// where tgt = heatmap(joint c)                        for c < 17
//       tgt = wp*heat(parent) + wc*heat(child)        for c >= 17
// with block-uniform wp, wc in {0,1} from the r = sign_eps(dz) logic.
__global__ __launch_bounds__(256) void slice_sum_kernel(
    const float* __restrict__ joints,   // [B,17,3]
    const float* __restrict__ middle,   // [B,59,64,64]
    const float* __restrict__ joint2d,  // [B,17,2]
    float* __restrict__ partial)        // [B,59]
{
    const int c   = blockIdx.x;   // 0..58
    const int b   = blockIdx.y;   // 0..255
    const int tid = threadIdx.x;  // 0..255

    // ---- block-uniform setup (scalar path) ----
    float wp = 0.f, wc = 0.f;
    int jp = 0, jc = 0;
    if (c < NJ) {
        jp = c; wp = 1.f;
    } else {
        const int pi = c - NJ;
        const int p  = pi / 3;
        const int ch = pi - p * 3;
        jp = c_par0[p];
        jc = c_par1[p];
        const float dz = joints[(b * NJ + jp) * 3 + 2] - joints[(b * NJ + jc) * 3 + 2];
        const int r = (dz > 0.1f) ? 1 : ((fabsf(dz) < 0.1f) ? 0 : -1);
        if (ch == 0)      { wp = 0.f; wc = (r == -1) ? 1.f : 0.f; }
        else if (ch == 1) { wp = 1.f; wc = (r ==  0) ? 1.f : 0.f; }
        else              { wp = 0.f; wc = (r ==  1) ? 1.f : 0.f; }
    }

    // heatmap params: h(i,k) = exp(-0.25*((i-x)^2+(k-y)^2 - d2min))
    // d2min at the clamped nearest-integer grid point (== grid max of the gaussian)
    float xp = 0.f, yp = 0.f, mp = 0.f;
    float xq = 0.f, yq = 0.f, mq = 0.f;
    if (wp != 0.f) {
        xp = joint2d[(b * NJ + jp) * 2 + 0] * 64.f;
        yp = joint2d[(b * NJ + jp) * 2 + 1] * 64.f;
        const float rx = fminf(fmaxf(floorf(xp + 0.5f), 0.f), 63.f);
        const float ry = fminf(fmaxf(floorf(yp + 0.5f), 0.f), 63.f);
        mp = (rx - xp) * (rx - xp) + (ry - yp) * (ry - yp);
    }
    if (wc != 0.f) {
        xq = joint2d[(b * NJ + jc) * 2 + 0] * 64.f;
        yq = joint2d[(b * NJ + jc) * 2 + 1] * 64.f;
        const float rx = fminf(fmaxf(floorf(xq + 0.5f), 0.f), 63.f);
        const float ry = fminf(fmaxf(floorf(yq + 0.5f), 0.f), 63.f);
        mq = (rx - xq) * (rx - xq) + (ry - yq) * (ry - yq);
    }

    const float4* __restrict__ src =
        (const float4*)(middle + ((size_t)b * NCH + c) * 4096);

    float acc = 0.f;
    #pragma unroll
    for (int v = 0; v < 4; ++v) {
        const int idx  = tid + v * 256;      // float4 index 0..1023
        const float4 m4 = src[idx];
        const int cell = idx * 4;            // k0 = cell&63 <= 60, same row for 4 lanes
        const float fi = (float)(cell >> 6);
        const float k0 = (float)(cell & 63);
        const float mv[4] = {m4.x, m4.y, m4.z, m4.w};
        #pragma unroll
        for (int q = 0; q < 4; ++q) {
            const float fk = k0 + (float)q;
            float tgt = 0.f;
            if (wp != 0.f) {  // block-uniform branch
                const float dx = fi - xp, dy = fk - yp;
                tgt += __expf(-0.25f * (dx * dx + dy * dy - mp));
            }
            if (wc != 0.f) {  // block-uniform branch
                const float dx = fi - xq, dy = fk - yq;
                tgt += __expf(-0.25f * (dx * dx + dy * dy - mq));
            }
            const float d = tgt - mv[q];
            acc += d * d;
        }
    }

    // ---- block reduction: wave shuffle, then 4 wave leaders via LDS ----
    #pragma unroll
    for (int off = 32; off > 0; off >>= 1)
        acc += __shfl_down(acc, off, 64);

    __shared__ float sred[4];
    if ((tid & 63) == 0) sred[tid >> 6] = acc;
    __syncthreads();
    if (tid == 0)
        partial[b * NCH + c] = sred[0] + sred[1] + sred[2] + sred[3];
}

// Single-block finalize: l3d + combine partials into the scalar loss.
__global__ __launch_bounds__(1024) void finalize_kernel(
    const float* __restrict__ pred,     // [B,17,3]
    const float* __restrict__ joints,   // [B,17,3]
    const float* __restrict__ partial,  // [B,59]
    float* __restrict__ out)            // [1]
{
    const int tid = threadIdx.x;
    double a = 0.0;

    // l3d total: sum |joints - pred| over all B*17*3
    for (int i = tid; i < BATCH * NJ * 3; i += 1024)
        a += (double)fabsf(joints[i] - pred[i]);

    double s2 = 0.0;  // L2D total + LHEM total (both get 0.005 weight)

    // L2D: sum of the first 17 partials per batch element
    for (int i = tid; i < BATCH * NJ; i += 1024) {
        const int b = i / NJ;
        const int c = i - b * NJ;
        s2 += (double)partial[b * NCH + c];
    }

    // LHEM: per (b, pair): (sqrt(S0)+sqrt(S1)+sqrt(S2))^2
    for (int i = tid; i < BATCH * NP; i += 1024) {
        const int b = i / NP;
        const int p = i - b * NP;
        const float* s = partial + b * NCH + NJ + p * 3;
        const float n = sqrtf(s[0]) + sqrtf(s[1]) + sqrtf(s[2]);
        s2 += (double)n * (double)n;
    }

    a += 0.005 * s2;

    __shared__ double sh[1024];
    sh[tid] = a;
    __syncthreads();
    #pragma unroll
    for (int off = 512; off > 0; off >>= 1) {
        if (tid < off) sh[tid] += sh[tid + off];
        __syncthreads();
    }
    if (tid == 0) out[0] = (float)(sh[0] * (1.0 / 256.0));
}

extern "C" void kernel_launch(void* const* d_in, const int* in_sizes, int n_in,
                              void* d_out, int out_size, void* d_ws, size_t ws_size,
                              hipStream_t stream) {
    const float* pred    = (const float*)d_in[0];
    const float* joints  = (const float*)d_in[1];
    const float* middle  = (const float*)d_in[2];
    const float* joint2d = (const float*)d_in[3];
    float* out     = (float*)d_out;
    float* partial = (float*)d_ws;   // B*59 floats; fully written before read

    dim3 grid(NCH, BATCH);
    slice_sum_kernel<<<grid, 256, 0, stream>>>(joints, middle, joint2d, partial);
    finalize_kernel<<<1, 1024, 0, stream>>>(pred, joints, partial, out);
}